// Round 4
// baseline (441.576 us; speedup 1.0000x reference)
//
#include <hip/hip_runtime.h>
#include <stdint.h>

// out[e] = edge_attr[e] / segsum(edge_attr, row)[col[e]]
//
// Fast path: bucketed two-phase reduction with EXACT bucket sizing
// (round 3 failed from a guessed per-bucket capacity: only ceil(N/4096)=245
// buckets are active, so the real mean is E/245=81920, not E/256 -> overflow).
//   P0 zero:    per-bucket histogram counters.
//   P1 hist:    global per-bucket edge counts (LDS hist -> padded atomics).
//   P2 scan:    exclusive scan (counts rounded to even -> 16B-aligned bases).
//   P3 scatter: per 4096-edge tile: LDS hist -> wave-0 shfl scan -> reload +
//               LDS-cursor rank -> coalesced nt pair flush at exact offsets.
//   P4 reduce:  2 blocks/bucket stream pairs (nt), LDS f32 bins -> partials.
//   P5 recip:   rnorm[i] = 1/(p0[i]+p1[i]).
//   P6 gather:  out[e] = rnorm[col[e]] * attr[e], 4x unroll, nt streaming.
// Fallback (small ws): direct-atomic version.

typedef int      v4i __attribute__((ext_vector_type(4)));
typedef float    v4f __attribute__((ext_vector_type(4)));
typedef unsigned v4u __attribute__((ext_vector_type(4)));
using ull = unsigned long long;

#define BKT_BITS 12
#define BKT_W    (1 << BKT_BITS)            // 4096 nodes per bucket
#define NB       256                         // supports N <= 1,048,576
#define NMAX     (NB << BKT_BITS)
#define TILE     4096
#define BLOCK1   512
#define TAILPAD  8
#define BLOCK2   1024

// ---------------- fast path ----------------

__global__ void zero_hist_kernel(int* __restrict__ ghist) {
    ghist[blockIdx.x * blockDim.x + threadIdx.x] = 0;
}

__global__ __launch_bounds__(256) void hist_kernel(
    const int* __restrict__ row, int* __restrict__ ghist, int E)
{
    __shared__ int h[NB];
    const int t = threadIdx.x;
    h[t] = 0;
    __syncthreads();

    const int gid = blockIdx.x * 256 + t;
    const int gstride = gridDim.x * 256;
    const int E4 = E >> 2;
    for (int i = gid; i < E4; i += gstride) {
        const v4i r = __builtin_nontemporal_load(reinterpret_cast<const v4i*>(row) + i);
        atomicAdd(&h[r.x >> BKT_BITS], 1);
        atomicAdd(&h[r.y >> BKT_BITS], 1);
        atomicAdd(&h[r.z >> BKT_BITS], 1);
        atomicAdd(&h[r.w >> BKT_BITS], 1);
    }
    for (int e = (E4 << 2) + gid; e < E; e += gstride)
        atomicAdd(&h[row[e] >> BKT_BITS], 1);
    __syncthreads();

    const int c = h[t];
    if (c > 0) atomicAdd(&ghist[t * TAILPAD], c);
}

__global__ __launch_bounds__(NB) void scan_kernel(
    const int* __restrict__ ghist, int* __restrict__ bases, int* __restrict__ cursors)
{
    __shared__ int s[NB];
    const int t = threadIdx.x;
    const int cnt = ghist[t * TAILPAD];
    const int rc  = (cnt + 1) & ~1;          // even-rounded -> 16B-aligned regions
    s[t] = rc;
    __syncthreads();
    for (int off = 1; off < NB; off <<= 1) {
        const int v = (t >= off) ? s[t - off] : 0;
        __syncthreads();
        s[t] += v;
        __syncthreads();
    }
    const int excl = s[t] - rc;
    bases[t] = excl;
    cursors[t * TAILPAD] = excl;
}

__global__ __launch_bounds__(BLOCK1) void scatter_kernel(
    const int* __restrict__ row, const float* __restrict__ attr,
    ull* __restrict__ pairsG, int* __restrict__ cursors, int E)
{
    __shared__ int hist[NB];
    __shared__ int scanb[NB];
    __shared__ int cursor[NB];
    __shared__ int gbase[NB];
    __shared__ ull pairs[TILE];

    const int  t    = threadIdx.x;
    const long base = (long)blockIdx.x * TILE;
    const bool full = (base + TILE <= (long)E);

    if (t < NB) hist[t] = 0;
    __syncthreads();

    // Pass A: local histogram (regular loads keep the tile L2-hot for pass B)
    if (full) {
        #pragma unroll
        for (int k = 0; k < 2; ++k) {
            const long e0 = base + ((long)(k * BLOCK1 + t) << 2);
            const v4i rv = *reinterpret_cast<const v4i*>(row + e0);
            atomicAdd(&hist[rv.x >> BKT_BITS], 1);
            atomicAdd(&hist[rv.y >> BKT_BITS], 1);
            atomicAdd(&hist[rv.z >> BKT_BITS], 1);
            atomicAdd(&hist[rv.w >> BKT_BITS], 1);
        }
    } else {
        for (int k = 0; k < 2; ++k) {
            const long e0 = base + ((long)(k * BLOCK1 + t) << 2);
            for (int j = 0; j < 4; ++j)
                if (e0 + j < (long)E) atomicAdd(&hist[row[e0 + j] >> BKT_BITS], 1);
        }
    }
    __syncthreads();

    // Wave-0 exclusive scan of the 256 bins (barrier-free within the wave)
    if (t < 64) {
        const int h0 = hist[t*4+0], h1 = hist[t*4+1], h2 = hist[t*4+2], h3 = hist[t*4+3];
        const int sum = h0 + h1 + h2 + h3;
        int x = sum;
        #pragma unroll
        for (int off = 1; off < 64; off <<= 1) {
            const int y = __shfl_up(x, off);
            if (t >= off) x += y;
        }
        const int excl = x - sum;
        scanb[t*4+0] = excl;           cursor[t*4+0] = excl;
        scanb[t*4+1] = excl + h0;      cursor[t*4+1] = excl + h0;
        scanb[t*4+2] = excl + h0 + h1; cursor[t*4+2] = excl + h0 + h1;
        scanb[t*4+3] = excl + h0 + h1 + h2;
        cursor[t*4+3] = excl + h0 + h1 + h2;
    }
    if (t < NB) {
        const int cnt = hist[t];
        if (cnt > 0) gbase[t] = atomicAdd(&cursors[t * TAILPAD], cnt);
    }
    __syncthreads();

    // Pass B: reload (L2-hot), rank via LDS cursor, stage pair in LDS
    if (full) {
        #pragma unroll
        for (int k = 0; k < 2; ++k) {
            const long e0 = base + ((long)(k * BLOCK1 + t) << 2);
            const v4i rv = __builtin_nontemporal_load(reinterpret_cast<const v4i*>(row + e0));
            const v4f av = __builtin_nontemporal_load(reinterpret_cast<const v4f*>(attr + e0));
            int p;
            p = atomicAdd(&cursor[rv.x >> BKT_BITS], 1);
            pairs[p] = ((ull)__float_as_uint(av.x) << 32) | (unsigned)rv.x;
            p = atomicAdd(&cursor[rv.y >> BKT_BITS], 1);
            pairs[p] = ((ull)__float_as_uint(av.y) << 32) | (unsigned)rv.y;
            p = atomicAdd(&cursor[rv.z >> BKT_BITS], 1);
            pairs[p] = ((ull)__float_as_uint(av.z) << 32) | (unsigned)rv.z;
            p = atomicAdd(&cursor[rv.w >> BKT_BITS], 1);
            pairs[p] = ((ull)__float_as_uint(av.w) << 32) | (unsigned)rv.w;
        }
    } else {
        for (int k = 0; k < 2; ++k) {
            const long e0 = base + ((long)(k * BLOCK1 + t) << 2);
            for (int j = 0; j < 4; ++j) {
                if (e0 + j < (long)E) {
                    const int r = row[e0 + j];
                    const float a = attr[e0 + j];
                    const int p = atomicAdd(&cursor[r >> BKT_BITS], 1);
                    pairs[p] = ((ull)__float_as_uint(a) << 32) | (unsigned)r;
                }
            }
        }
    }
    __syncthreads();

    // Flush: bucket-contiguous runs; offsets exact by construction
    const int total = full ? TILE : (int)((long)E - base);
    for (int s = t; s < total; s += BLOCK1) {
        const ull p  = pairs[s];
        const int bb = (int)(((unsigned)p) >> BKT_BITS);
        const long dst = (long)gbase[bb] + (s - scanb[bb]);
        __builtin_nontemporal_store(p, pairsG + (size_t)dst);
    }
}

__global__ __launch_bounds__(BLOCK2) void bucket_reduce_kernel(
    const ull* __restrict__ pairsG, const int* __restrict__ ghist,
    const int* __restrict__ bases, float* __restrict__ partial,
    const int* __restrict__ Np)
{
    __shared__ float bins[BKT_W];                      // 16 KB
    const int N  = *Np;
    const int nB = (N + BKT_W - 1) >> BKT_BITS;
    const int b    = blockIdx.x >> 1;
    const int half = blockIdx.x & 1;
    if (b >= nB) return;

    for (int i = threadIdx.x; i < BKT_W; i += BLOCK2) bins[i] = 0.0f;
    __syncthreads();

    const int cnt = ghist[b * TAILPAD];
    const ull* src = pairsG + (size_t)bases[b];        // even base -> 16B aligned

    const int Q = cnt >> 2;                            // 4-pair quads
    for (int q = half * BLOCK2 + threadIdx.x; q < Q; q += 2 * BLOCK2) {
        const v4u p0 = __builtin_nontemporal_load(reinterpret_cast<const v4u*>(src + 4*q));
        const v4u p1 = __builtin_nontemporal_load(reinterpret_cast<const v4u*>(src + 4*q + 2));
        atomicAdd(&bins[p0.x & (BKT_W-1)], __uint_as_float(p0.y));
        atomicAdd(&bins[p0.z & (BKT_W-1)], __uint_as_float(p0.w));
        atomicAdd(&bins[p1.x & (BKT_W-1)], __uint_as_float(p1.y));
        atomicAdd(&bins[p1.z & (BKT_W-1)], __uint_as_float(p1.w));
    }
    const int rem = cnt - (Q << 2);
    if (half == 0 && threadIdx.x < rem) {
        const ull p = src[(Q << 2) + threadIdx.x];
        atomicAdd(&bins[(unsigned)p & (BKT_W-1)], __uint_as_float((unsigned)(p >> 32)));
    }
    __syncthreads();

    const int lo = b << BKT_BITS;
    float* dst = partial + (size_t)half * NMAX + lo;
    for (int i = threadIdx.x; i < BKT_W; i += BLOCK2)
        __builtin_nontemporal_store(bins[i], dst + i);
}

__global__ void recip2_kernel(const float* __restrict__ partial,
                              float* __restrict__ rnorm, const int* __restrict__ Np) {
    const int N = *Np;
    const int stride = gridDim.x * blockDim.x;
    const float* p0 = partial;
    const float* p1 = partial + NMAX;
    for (int i = blockIdx.x * blockDim.x + threadIdx.x; i < N; i += stride)
        rnorm[i] = 1.0f / (p0[i] + p1[i]);
}

// ---------------- gather pass (shared) ----------------

__global__ __launch_bounds__(256) void gather_scale_kernel(
    const int* __restrict__ col, const float* __restrict__ attr,
    const float* __restrict__ rnorm, float* __restrict__ out, int E)
{
    const int tid = blockIdx.x * blockDim.x + threadIdx.x;
    const int stride = gridDim.x * blockDim.x;
    const int E4 = E >> 2;
    const v4i* col4  = reinterpret_cast<const v4i*>(col);
    const v4f* attr4 = reinterpret_cast<const v4f*>(attr);
    v4f*       out4  = reinterpret_cast<v4f*>(out);

    int i = tid;
    for (; i + 3 * stride < E4; i += 4 * stride) {       // 16 random loads in flight
        const v4i c0 = __builtin_nontemporal_load(col4 + i);
        const v4i c1 = __builtin_nontemporal_load(col4 + i + stride);
        const v4i c2 = __builtin_nontemporal_load(col4 + i + 2 * stride);
        const v4i c3 = __builtin_nontemporal_load(col4 + i + 3 * stride);
        const v4f a0 = __builtin_nontemporal_load(attr4 + i);
        const v4f a1 = __builtin_nontemporal_load(attr4 + i + stride);
        const v4f a2 = __builtin_nontemporal_load(attr4 + i + 2 * stride);
        const v4f a3 = __builtin_nontemporal_load(attr4 + i + 3 * stride);
        v4f o0, o1, o2, o3;
        o0.x = rnorm[c0.x] * a0.x; o0.y = rnorm[c0.y] * a0.y;
        o0.z = rnorm[c0.z] * a0.z; o0.w = rnorm[c0.w] * a0.w;
        o1.x = rnorm[c1.x] * a1.x; o1.y = rnorm[c1.y] * a1.y;
        o1.z = rnorm[c1.z] * a1.z; o1.w = rnorm[c1.w] * a1.w;
        o2.x = rnorm[c2.x] * a2.x; o2.y = rnorm[c2.y] * a2.y;
        o2.z = rnorm[c2.z] * a2.z; o2.w = rnorm[c2.w] * a2.w;
        o3.x = rnorm[c3.x] * a3.x; o3.y = rnorm[c3.y] * a3.y;
        o3.z = rnorm[c3.z] * a3.z; o3.w = rnorm[c3.w] * a3.w;
        __builtin_nontemporal_store(o0, out4 + i);
        __builtin_nontemporal_store(o1, out4 + i + stride);
        __builtin_nontemporal_store(o2, out4 + i + 2 * stride);
        __builtin_nontemporal_store(o3, out4 + i + 3 * stride);
    }
    for (; i < E4; i += stride) {
        const v4i c = __builtin_nontemporal_load(col4 + i);
        const v4f a = __builtin_nontemporal_load(attr4 + i);
        v4f o;
        o.x = rnorm[c.x] * a.x; o.y = rnorm[c.y] * a.y;
        o.z = rnorm[c.z] * a.z; o.w = rnorm[c.w] * a.w;
        __builtin_nontemporal_store(o, out4 + i);
    }
    for (int e = (E4 << 2) + tid; e < E; e += stride)
        out[e] = rnorm[col[e]] * attr[e];
}

// ---------------- fallback path ----------------

__global__ void zero_ws_kernel(float* __restrict__ ws, const int* __restrict__ Np) {
    const int N = *Np;
    const int stride = gridDim.x * blockDim.x;
    for (int i = blockIdx.x * blockDim.x + threadIdx.x; i < N; i += stride)
        ws[i] = 0.0f;
}

__global__ void rowsum_atomic_kernel(const int* __restrict__ row,
                                     const float* __restrict__ attr,
                                     float* __restrict__ rowsum, int E) {
    const int tid = blockIdx.x * blockDim.x + threadIdx.x;
    const int stride = gridDim.x * blockDim.x;
    const int E4 = E >> 2;
    for (int i = tid; i < E4; i += stride) {
        const int4   r = reinterpret_cast<const int4*>(row)[i];
        const float4 a = reinterpret_cast<const float4*>(attr)[i];
        atomicAdd(&rowsum[r.x], a.x);
        atomicAdd(&rowsum[r.y], a.y);
        atomicAdd(&rowsum[r.z], a.z);
        atomicAdd(&rowsum[r.w], a.w);
    }
    for (int i = (E4 << 2) + tid; i < E; i += stride)
        atomicAdd(&rowsum[row[i]], attr[i]);
}

__global__ void recip_kernel(float* __restrict__ rowsum, const int* __restrict__ Np) {
    const int N = *Np;
    const int stride = gridDim.x * blockDim.x;
    for (int i = blockIdx.x * blockDim.x + threadIdx.x; i < N; i += stride)
        rowsum[i] = 1.0f / rowsum[i];
}

// ---------------- launch ----------------

extern "C" void kernel_launch(void* const* d_in, const int* in_sizes, int n_in,
                              void* d_out, int out_size, void* d_ws, size_t ws_size,
                              hipStream_t stream) {
    const int*   edge_index = (const int*)d_in[0];     // [2, E]
    const float* edge_attr  = (const float*)d_in[1];   // [E]
    const int*   Np         = (const int*)d_in[2];     // scalar N (device)

    const int E = in_sizes[1];
    const int* row = edge_index;
    const int* col = edge_index + E;
    float* out = (float*)d_out;

    // ws layout (16B-aligned chunks)
    size_t off = 0;
    auto align256 = [](size_t x) { return (x + 255) & ~(size_t)255; };
    const size_t ghistOff   = off; off = align256(off + (size_t)NB * TAILPAD * sizeof(int));
    const size_t basesOff   = off; off = align256(off + (size_t)NB * sizeof(int));
    const size_t cursorsOff = off; off = align256(off + (size_t)NB * TAILPAD * sizeof(int));
    const size_t rnormOff   = off; off = align256(off + (size_t)NMAX * sizeof(float));
    const size_t partOff    = off; off = align256(off + 2 * (size_t)NMAX * sizeof(float));
    const size_t pairsOff   = off; off += ((size_t)E + 2 * NB) * sizeof(ull);
    const size_t need = off;

    if (ws_size >= need) {
        int*   ghist   = (int*)  ((char*)d_ws + ghistOff);
        int*   bases   = (int*)  ((char*)d_ws + basesOff);
        int*   cursors = (int*)  ((char*)d_ws + cursorsOff);
        float* rnorm   = (float*)((char*)d_ws + rnormOff);
        float* partial = (float*)((char*)d_ws + partOff);
        ull*   pairs   = (ull*)  ((char*)d_ws + pairsOff);

        const int nTiles = (E + TILE - 1) / TILE;
        zero_hist_kernel    <<<(NB * TAILPAD + 255) / 256, 256, 0, stream>>>(ghist);
        hist_kernel         <<<1024, 256, 0, stream>>>(row, ghist, E);
        scan_kernel         <<<1, NB, 0, stream>>>(ghist, bases, cursors);
        scatter_kernel      <<<nTiles, BLOCK1, 0, stream>>>(row, edge_attr, pairs, cursors, E);
        bucket_reduce_kernel<<<2 * NB, BLOCK2, 0, stream>>>(pairs, ghist, bases, partial, Np);
        recip2_kernel       <<<1024, 256, 0, stream>>>(partial, rnorm, Np);
        gather_scale_kernel <<<2048, 256, 0, stream>>>(col, edge_attr, rnorm, out, E);
    } else {
        float* rowsum = (float*)d_ws;
        const int workE = (E + 3) >> 2;
        int gE = (workE + 255) / 256;
        if (gE > 2048) gE = 2048;
        zero_ws_kernel      <<<2048, 256, 0, stream>>>(rowsum, Np);
        rowsum_atomic_kernel<<<gE, 256, 0, stream>>>(row, edge_attr, rowsum, E);
        recip_kernel        <<<2048, 256, 0, stream>>>(rowsum, Np);
        gather_scale_kernel <<<2048, 256, 0, stream>>>(col, edge_attr, rowsum, out, E);
    }
}

// Round 5
// 397.959 us; speedup vs baseline: 1.1096x; 1.1096x over previous
//
#include <hip/hip_runtime.h>
#include <stdint.h>

// out[e] = edge_attr[e] / segsum(edge_attr, row)[col[e]]
//
// Fast path: counting-sort by 8192-wide node bucket with EXACT, ATOMIC-FREE
// scatter offsets (round 4's scatter was stall-bound: per-tile global cursor
// atomics + double row read + 75% occupancy + 133B write runs).
//   P1 hist:    per-tile bucket histogram -> histG[tile][b]      (80 MB read)
//   P2 totals:  totals[b] = sum_t histG[t][b]
//   P3 bases:   exclusive scan of even-rounded totals -> bases[b]
//   P4 offsets: per-bucket exclusive scan over tiles -> offG[t][b]
//   P5 scatter: regs-resident tile, 1 LDS-atomic rank round, wave0 shfl scan,
//               LDS stage, coalesced nt flush at exact offsets (no atomics)
//   P6 reduce:  nSplit blocks/bucket stream pairs, LDS f32 bins -> partials
//   P7 recip:   partial[0][i] = 1/sum_q partial[q][i]   (in place)
//   P8 gather:  out[e] = partial0[col[e]] * attr[e], 4x unroll, nt streams
// Fallback (small ws): direct-atomic version.

typedef int      v4i __attribute__((ext_vector_type(4)));
typedef float    v4f __attribute__((ext_vector_type(4)));
typedef unsigned v4u __attribute__((ext_vector_type(4)));
using ull = unsigned long long;

#define BKT_BITS 13
#define BKT_W    (1 << BKT_BITS)      // 8192 nodes per bucket
#define NB       128                   // supports N <= 1,048,576
#define NMAX     (NB << BKT_BITS)
#define TILE     4096
#define BLOCK1   512
#define BLOCK2   1024

// ---------------- fast path ----------------

__global__ __launch_bounds__(BLOCK1) void hist_kernel(
    const int* __restrict__ row, int* __restrict__ histG, int E)
{
    __shared__ int h[NB];
    const int t = threadIdx.x;
    const long base = (long)blockIdx.x * TILE;
    if (t < NB) h[t] = 0;
    __syncthreads();
    if (base + TILE <= (long)E) {
        #pragma unroll
        for (int k = 0; k < 2; ++k) {
            const long e0 = base + ((long)(k * BLOCK1 + t) << 2);
            const v4i rv = *reinterpret_cast<const v4i*>(row + e0);   // keep L2/L3-hot
            atomicAdd(&h[rv.x >> BKT_BITS], 1);
            atomicAdd(&h[rv.y >> BKT_BITS], 1);
            atomicAdd(&h[rv.z >> BKT_BITS], 1);
            atomicAdd(&h[rv.w >> BKT_BITS], 1);
        }
    } else {
        for (int k = 0; k < 2; ++k) {
            const long e0 = base + ((long)(k * BLOCK1 + t) << 2);
            for (int j = 0; j < 4; ++j)
                if (e0 + j < (long)E) atomicAdd(&h[row[e0 + j] >> BKT_BITS], 1);
        }
    }
    __syncthreads();
    if (t < NB) histG[(size_t)blockIdx.x * NB + t] = h[t];
}

__global__ __launch_bounds__(256) void totals_kernel(
    const int* __restrict__ histG, int* __restrict__ totals, int nTiles)
{
    __shared__ int s[256];
    const int b = blockIdx.x;
    int acc = 0;
    for (int t = threadIdx.x; t < nTiles; t += 256)
        acc += histG[(size_t)t * NB + b];
    s[threadIdx.x] = acc;
    __syncthreads();
    for (int o = 128; o > 0; o >>= 1) {
        if (threadIdx.x < o) s[threadIdx.x] += s[threadIdx.x + o];
        __syncthreads();
    }
    if (threadIdx.x == 0) totals[b] = s[0];
}

__global__ __launch_bounds__(NB) void bases_kernel(
    const int* __restrict__ totals, int* __restrict__ bases)
{
    __shared__ int s[NB];
    const int t = threadIdx.x;
    const int rc = (totals[t] + 1) & ~1;      // even-rounded -> 16B-aligned regions
    s[t] = rc;
    __syncthreads();
    for (int off = 1; off < NB; off <<= 1) {
        const int v = (t >= off) ? s[t - off] : 0;
        __syncthreads();
        s[t] += v;
        __syncthreads();
    }
    bases[t] = s[t] - rc;
}

__global__ __launch_bounds__(256) void offsets_kernel(
    const int* __restrict__ histG, const int* __restrict__ bases,
    int* __restrict__ offG, int nTiles)
{
    __shared__ int s[256];
    const int b = blockIdx.x;
    const int seg = (nTiles + 255) >> 8;
    const int t0 = threadIdx.x * seg;
    int acc = 0;
    for (int k = 0; k < seg; ++k) {
        const int t = t0 + k;
        if (t < nTiles) acc += histG[(size_t)t * NB + b];
    }
    s[threadIdx.x] = acc;
    __syncthreads();
    for (int off = 1; off < 256; off <<= 1) {
        const int v = (threadIdx.x >= off) ? s[threadIdx.x - off] : 0;
        __syncthreads();
        s[threadIdx.x] += v;
        __syncthreads();
    }
    int run = bases[b] + s[threadIdx.x] - acc;     // exclusive base for my segment
    for (int k = 0; k < seg; ++k) {
        const int t = t0 + k;
        if (t < nTiles) {
            offG[(size_t)t * NB + b] = run;
            run += histG[(size_t)t * NB + b];
        }
    }
}

__global__ __launch_bounds__(BLOCK1) void scatter_kernel(
    const int* __restrict__ row, const float* __restrict__ attr,
    const int* __restrict__ offG, ull* __restrict__ pairsG, int E)
{
    __shared__ int cnt[NB];
    __shared__ int scanb[NB];
    __shared__ int gbase[NB];
    __shared__ ull pairs[TILE];                    // 32 KB

    const int  t    = threadIdx.x;
    const long base = (long)blockIdx.x * TILE;
    const bool full = (base + TILE <= (long)E);

    if (t < NB) cnt[t] = 0;
    __syncthreads();

    int r[8]; float a[8]; int rk[8];
    if (full) {
        #pragma unroll
        for (int k = 0; k < 2; ++k) {
            const long e0 = base + ((long)(k * BLOCK1 + t) << 2);
            const v4i rv = __builtin_nontemporal_load(reinterpret_cast<const v4i*>(row + e0));
            const v4f av = __builtin_nontemporal_load(reinterpret_cast<const v4f*>(attr + e0));
            r[k*4+0]=rv.x; r[k*4+1]=rv.y; r[k*4+2]=rv.z; r[k*4+3]=rv.w;
            a[k*4+0]=av.x; a[k*4+1]=av.y; a[k*4+2]=av.z; a[k*4+3]=av.w;
        }
        #pragma unroll
        for (int i = 0; i < 8; ++i)
            rk[i] = atomicAdd(&cnt[r[i] >> BKT_BITS], 1);
    } else {
        for (int k = 0; k < 2; ++k) {
            const long e0 = base + ((long)(k * BLOCK1 + t) << 2);
            for (int j = 0; j < 4; ++j) {
                const int i = k*4 + j;
                if (e0 + j < (long)E) {
                    r[i] = row[e0 + j]; a[i] = attr[e0 + j];
                    rk[i] = atomicAdd(&cnt[r[i] >> BKT_BITS], 1);
                } else r[i] = -1;
            }
        }
    }
    __syncthreads();

    // wave-0 exclusive scan of the 128 bucket counts (2 bins/lane)
    if (t < 64) {
        const int h0 = cnt[2*t], h1 = cnt[2*t+1];
        const int sum = h0 + h1;
        int x = sum;
        #pragma unroll
        for (int off = 1; off < 64; off <<= 1) {
            const int y = __shfl_up(x, off);
            if (t >= off) x += y;
        }
        const int excl = x - sum;
        scanb[2*t]   = excl;
        scanb[2*t+1] = excl + h0;
    }
    if (t < NB) gbase[t] = offG[(size_t)blockIdx.x * NB + t];   // exact, no atomic
    __syncthreads();

    #pragma unroll
    for (int i = 0; i < 8; ++i)
        if (r[i] >= 0)
            pairs[scanb[r[i] >> BKT_BITS] + rk[i]] =
                ((ull)__float_as_uint(a[i]) << 32) | (unsigned)r[i];
    __syncthreads();

    const int total = full ? TILE : (int)((long)E - base);
    for (int s = t; s < total; s += BLOCK1) {
        const ull p  = pairs[s];
        const int bb = (int)(((unsigned)p) >> BKT_BITS);
        const size_t dst = (size_t)gbase[bb] + (size_t)(s - scanb[bb]);
        __builtin_nontemporal_store(p, pairsG + dst);
    }
}

__global__ __launch_bounds__(BLOCK2) void reduce_kernel(
    const ull* __restrict__ pairsG, const int* __restrict__ totals,
    const int* __restrict__ bases, float* __restrict__ partial, int nSplit)
{
    __shared__ float bins[BKT_W];                  // 32 KB
    const int b = blockIdx.x / nSplit;
    const int q = blockIdx.x % nSplit;
    for (int i = threadIdx.x; i < BKT_W; i += BLOCK2) bins[i] = 0.0f;
    __syncthreads();

    const int cnt = totals[b];
    const ull* src = pairsG + (size_t)bases[b];    // even base -> 16B aligned
    const int Q = cnt >> 2;
    for (int i = q * BLOCK2 + threadIdx.x; i < Q; i += nSplit * BLOCK2) {
        const v4u p0 = __builtin_nontemporal_load(reinterpret_cast<const v4u*>(src + 4*(size_t)i));
        const v4u p1 = __builtin_nontemporal_load(reinterpret_cast<const v4u*>(src + 4*(size_t)i + 2));
        atomicAdd(&bins[p0.x & (BKT_W-1)], __uint_as_float(p0.y));
        atomicAdd(&bins[p0.z & (BKT_W-1)], __uint_as_float(p0.w));
        atomicAdd(&bins[p1.x & (BKT_W-1)], __uint_as_float(p1.y));
        atomicAdd(&bins[p1.z & (BKT_W-1)], __uint_as_float(p1.w));
    }
    const int rem = cnt - (Q << 2);
    if (q == 0 && threadIdx.x < rem) {
        const ull p = src[(Q << 2) + threadIdx.x];
        atomicAdd(&bins[(unsigned)p & (BKT_W-1)], __uint_as_float((unsigned)(p >> 32)));
    }
    __syncthreads();

    float* dst = partial + (size_t)q * NMAX + ((size_t)b << BKT_BITS);
    for (int i = threadIdx.x; i < BKT_W; i += BLOCK2)
        __builtin_nontemporal_store(bins[i], dst + i);
}

__global__ void recip_kernel(float* __restrict__ partial,
                             const int* __restrict__ Np, int nSplit) {
    const int N = *Np;
    const int stride = gridDim.x * blockDim.x;
    for (int i = blockIdx.x * blockDim.x + threadIdx.x; i < N; i += stride) {
        float s = 0.0f;
        for (int q = 0; q < nSplit; ++q) s += partial[(size_t)q * NMAX + i];
        partial[i] = 1.0f / s;                     // in place over partial[0]
    }
}

// ---------------- gather pass (shared) ----------------

__global__ __launch_bounds__(256) void gather_scale_kernel(
    const int* __restrict__ col, const float* __restrict__ attr,
    const float* __restrict__ rnorm, float* __restrict__ out, int E)
{
    const int tid = blockIdx.x * blockDim.x + threadIdx.x;
    const int stride = gridDim.x * blockDim.x;
    const int E4 = E >> 2;
    const v4i* col4  = reinterpret_cast<const v4i*>(col);
    const v4f* attr4 = reinterpret_cast<const v4f*>(attr);
    v4f*       out4  = reinterpret_cast<v4f*>(out);

    int i = tid;
    for (; i + 3 * stride < E4; i += 4 * stride) {       // 16 random loads in flight
        const v4i c0 = __builtin_nontemporal_load(col4 + i);
        const v4i c1 = __builtin_nontemporal_load(col4 + i + stride);
        const v4i c2 = __builtin_nontemporal_load(col4 + i + 2 * stride);
        const v4i c3 = __builtin_nontemporal_load(col4 + i + 3 * stride);
        const v4f a0 = __builtin_nontemporal_load(attr4 + i);
        const v4f a1 = __builtin_nontemporal_load(attr4 + i + stride);
        const v4f a2 = __builtin_nontemporal_load(attr4 + i + 2 * stride);
        const v4f a3 = __builtin_nontemporal_load(attr4 + i + 3 * stride);
        v4f o0, o1, o2, o3;
        o0.x = rnorm[c0.x] * a0.x; o0.y = rnorm[c0.y] * a0.y;
        o0.z = rnorm[c0.z] * a0.z; o0.w = rnorm[c0.w] * a0.w;
        o1.x = rnorm[c1.x] * a1.x; o1.y = rnorm[c1.y] * a1.y;
        o1.z = rnorm[c1.z] * a1.z; o1.w = rnorm[c1.w] * a1.w;
        o2.x = rnorm[c2.x] * a2.x; o2.y = rnorm[c2.y] * a2.y;
        o2.z = rnorm[c2.z] * a2.z; o2.w = rnorm[c2.w] * a2.w;
        o3.x = rnorm[c3.x] * a3.x; o3.y = rnorm[c3.y] * a3.y;
        o3.z = rnorm[c3.z] * a3.z; o3.w = rnorm[c3.w] * a3.w;
        __builtin_nontemporal_store(o0, out4 + i);
        __builtin_nontemporal_store(o1, out4 + i + stride);
        __builtin_nontemporal_store(o2, out4 + i + 2 * stride);
        __builtin_nontemporal_store(o3, out4 + i + 3 * stride);
    }
    for (; i < E4; i += stride) {
        const v4i c = __builtin_nontemporal_load(col4 + i);
        const v4f a = __builtin_nontemporal_load(attr4 + i);
        v4f o;
        o.x = rnorm[c.x] * a.x; o.y = rnorm[c.y] * a.y;
        o.z = rnorm[c.z] * a.z; o.w = rnorm[c.w] * a.w;
        __builtin_nontemporal_store(o, out4 + i);
    }
    for (int e = (E4 << 2) + tid; e < E; e += stride)
        out[e] = rnorm[col[e]] * attr[e];
}

// ---------------- fallback path ----------------

__global__ void zero_ws_kernel(float* __restrict__ ws, const int* __restrict__ Np) {
    const int N = *Np;
    const int stride = gridDim.x * blockDim.x;
    for (int i = blockIdx.x * blockDim.x + threadIdx.x; i < N; i += stride)
        ws[i] = 0.0f;
}

__global__ void rowsum_atomic_kernel(const int* __restrict__ row,
                                     const float* __restrict__ attr,
                                     float* __restrict__ rowsum, int E) {
    const int tid = blockIdx.x * blockDim.x + threadIdx.x;
    const int stride = gridDim.x * blockDim.x;
    const int E4 = E >> 2;
    for (int i = tid; i < E4; i += stride) {
        const int4   r = reinterpret_cast<const int4*>(row)[i];
        const float4 a = reinterpret_cast<const float4*>(attr)[i];
        atomicAdd(&rowsum[r.x], a.x);
        atomicAdd(&rowsum[r.y], a.y);
        atomicAdd(&rowsum[r.z], a.z);
        atomicAdd(&rowsum[r.w], a.w);
    }
    for (int i = (E4 << 2) + tid; i < E; i += stride)
        atomicAdd(&rowsum[row[i]], attr[i]);
}

__global__ void recip_fallback_kernel(float* __restrict__ rowsum,
                                      const int* __restrict__ Np) {
    const int N = *Np;
    const int stride = gridDim.x * blockDim.x;
    for (int i = blockIdx.x * blockDim.x + threadIdx.x; i < N; i += stride)
        rowsum[i] = 1.0f / rowsum[i];
}

// ---------------- launch ----------------

extern "C" void kernel_launch(void* const* d_in, const int* in_sizes, int n_in,
                              void* d_out, int out_size, void* d_ws, size_t ws_size,
                              hipStream_t stream) {
    const int*   edge_index = (const int*)d_in[0];     // [2, E]
    const float* edge_attr  = (const float*)d_in[1];   // [E]
    const int*   Np         = (const int*)d_in[2];     // scalar N (device)

    const int E = in_sizes[1];
    const int* row = edge_index;
    const int* col = edge_index + E;
    float* out = (float*)d_out;

    const int nTiles = (E + TILE - 1) / TILE;
    auto align256 = [](size_t x) { return (x + 255) & ~(size_t)255; };

    size_t off = 0;
    const size_t basesOff  = off; off += align256(NB * sizeof(int));
    const size_t totalsOff = off; off += align256(NB * sizeof(int));
    const size_t partOff   = off;
    const size_t histBytes = align256((size_t)nTiles * NB * sizeof(int));
    const size_t scanBytes = 2 * histBytes;                    // histG + offG
    const size_t pairsBytes = ((size_t)E + 2 * NB) * sizeof(ull);

    int nSplit = 0;
    size_t partRegion = 0;
    for (int c : {8, 4, 2, 1}) {
        size_t pr = (size_t)c * NMAX * sizeof(float);
        if (pr < scanBytes) pr = scanBytes;
        if (partOff + pr + pairsBytes <= ws_size) { nSplit = c; partRegion = pr; break; }
    }

    if (nSplit > 0) {
        int*   bases   = (int*)  ((char*)d_ws + basesOff);
        int*   totals  = (int*)  ((char*)d_ws + totalsOff);
        float* partial = (float*)((char*)d_ws + partOff);
        int*   histG   = (int*)  ((char*)d_ws + partOff);           // alias: dead
        int*   offG    = (int*)  ((char*)d_ws + partOff + histBytes); // before reduce
        ull*   pairs   = (ull*)  ((char*)d_ws + partOff + partRegion);

        hist_kernel        <<<nTiles, BLOCK1, 0, stream>>>(row, histG, E);
        totals_kernel      <<<NB, 256, 0, stream>>>(histG, totals, nTiles);
        bases_kernel       <<<1, NB, 0, stream>>>(totals, bases);
        offsets_kernel     <<<NB, 256, 0, stream>>>(histG, bases, offG, nTiles);
        scatter_kernel     <<<nTiles, BLOCK1, 0, stream>>>(row, edge_attr, offG, pairs, E);
        reduce_kernel      <<<NB * nSplit, BLOCK2, 0, stream>>>(pairs, totals, bases, partial, nSplit);
        recip_kernel       <<<1024, 256, 0, stream>>>(partial, Np, nSplit);
        gather_scale_kernel<<<2048, 256, 0, stream>>>(col, edge_attr, partial, out, E);
    } else {
        float* rowsum = (float*)d_ws;
        const int workE = (E + 3) >> 2;
        int gE = (workE + 255) / 256;
        if (gE > 2048) gE = 2048;
        zero_ws_kernel       <<<2048, 256, 0, stream>>>(rowsum, Np);
        rowsum_atomic_kernel <<<gE, 256, 0, stream>>>(row, edge_attr, rowsum, E);
        recip_fallback_kernel<<<2048, 256, 0, stream>>>(rowsum, Np);
        gather_scale_kernel  <<<2048, 256, 0, stream>>>(col, edge_attr, rowsum, out, E);
    }
}